// Round 15
// baseline (635.207 us; speedup 1.0000x reference)
//
#include <hip/hip_runtime.h>
#include <stdint.h>

// ---------------- types ----------------
typedef float   f32x4 __attribute__((ext_vector_type(4)));
typedef float   f32x2 __attribute__((ext_vector_type(2)));
typedef __bf16  bfx8  __attribute__((ext_vector_type(8)));
typedef uint16_t u16x8 __attribute__((ext_vector_type(8)));
typedef uint16_t u16x4 __attribute__((ext_vector_type(4)));

#define AS1(p) ((__attribute__((address_space(1))) void*)(p))
#define AS3(p) ((__attribute__((address_space(3))) void*)(p))

__device__ __forceinline__ uint16_t f2bf(float f) {
    union { float f; uint32_t u; } c; c.f = f;
    uint32_t u = c.u;
    return (uint16_t)((u + 0x7FFFu + ((u >> 16) & 1u)) >> 16);
}
__device__ __forceinline__ float sigmoidf_(float x) { return 1.0f / (1.0f + __expf(-x)); }
__device__ __forceinline__ float frcp(float x) { float r; asm("v_rcp_f32 %0, %1" : "=v"(r) : "v"(x)); return r; }
__device__ __forceinline__ uint32_t cvtpk(float lo, float hi) {
    uint32_t r; asm("v_cvt_pk_bf16_f32 %0, %1, %2" : "=v"(r) : "v"(lo), "v"(hi)); return r;
}
// XCD-chunked bijective block swizzle (T1). Requires nwg % 8 == 0 (all our grids).
// Default dispatch round-robins linear id % 8 across XCDs; this remap gives each XCD a
// CONTIGUOUS chunk of tiles -> operand panels stay in one XCD's L2. Pure permutation.
__device__ __forceinline__ int xcd_swz(int lid, int nwg) {
    return (lid & 7) * (nwg >> 3) + (lid >> 3);
}

// ---------------- weight convert+transpose: fp32 [K][N] -> bf16 [N][K] ----------------
// arena layout (uint16 units):
//   wqkv: [L][1536][512]   @ 0         (q rows 0..511, k 512..1023, v 1024..1535)
//   wo  : [L][512][512]    @ 4718592
//   w1  : [L][512][512]    @ 6291456
//   w2  : [L][512][512]    @ 7864320
//   wemb: [512][128]       @ 9437184
__global__ __launch_bounds__(256) void wconv_k(
    const float* __restrict__ Wq, const float* __restrict__ Wk, const float* __restrict__ Wv,
    const float* __restrict__ Wo, const float* __restrict__ W1, const float* __restrict__ W2,
    const float* __restrict__ Wemb, uint16_t* __restrict__ arena)
{
    __shared__ uint16_t tl[64][65];
    const int z = blockIdx.z;
    const float* in; uint16_t* out; int K, N;
    if (z < 36) {
        const int type = z / 6, l = z % 6;
        const float* bases[6] = {Wq, Wk, Wv, Wo, W1, W2};
        in = bases[type] + (size_t)l * 512 * 512;
        K = 512; N = 512;
        if (type < 3) out = arena + (size_t)l * 786432u + (size_t)type * 262144u;
        else          out = arena + 4718592u + (size_t)(type - 3) * 1572864u + (size_t)l * 262144u;
    } else {
        if (blockIdx.y >= 2) return;      // K=128 -> only 2 k-tiles
        in = Wemb; K = 128; N = 512;
        out = arena + 9437184u;
    }
    const int n0 = blockIdx.x * 64, k0 = blockIdx.y * 64;
    const int t = threadIdx.x, r = t >> 2, seg = t & 3;
    const float* src = in + (size_t)(k0 + r) * N + n0 + seg * 16;
#pragma unroll
    for (int v2 = 0; v2 < 4; ++v2) {
        f32x4 d = *(const f32x4*)(src + v2 * 4);
#pragma unroll
        for (int j = 0; j < 4; ++j) tl[r][seg * 16 + v2 * 4 + j] = f2bf(d[j]);
    }
    __syncthreads();
    u16x8 o0, o1;
#pragma unroll
    for (int j = 0; j < 8; ++j) { o0[j] = tl[seg * 16 + j][r]; o1[j] = tl[seg * 16 + 8 + j][r]; }
    uint16_t* dst = out + (size_t)(n0 + r) * K + k0 + seg * 16;
    *(u16x8*)dst = o0; *(u16x8*)(dst + 8) = o1;
}

// ---------------- mean over ensemble M=10: features [B,M,S,F] -> bf16 [T][F] ----------------
__global__ __launch_bounds__(256) void fmean_k(const float* __restrict__ feat, uint16_t* __restrict__ fm)
{
    int id = blockIdx.x * 256 + threadIdx.x;      // 0 .. 4096*128-1
    int f = id & 127, row = id >> 7;              // row = b*1024+s
    int b = row >> 10, s = row & 1023;
    float acc = 0.f;
#pragma unroll
    for (int m = 0; m < 10; ++m)
        acc += feat[(size_t)((b * 10 + m) * 1024 + s) * 128 + f];
    fm[id] = f2bf(acc * 0.1f);
}

// ---------------- bf16 MFMA GEMM 64x64 tile, 2-phase pipelined ----------------
// C[M,N] = A[M,K] @ Bw^T. Bw is [N][Kb], Kb = KMOD ? 512 : Ksz (KMOD: logical K wraps
// mod 512 -> Wo reuse for split-O attention output by linearity).
// STATION: epilogue adds station embedding (NaN-gated per row) and writes bf16 x16
// (fuses the old station_k kernel into the embedding GEMM).
template<int BIAS, int SILU, int OUTBF, int KMOD, int STATION>
__global__ __launch_bounds__(256) void gemm64(const uint16_t* __restrict__ A,
    const uint16_t* __restrict__ Bw, const float* __restrict__ bias,
    void* __restrict__ Cout, int Msz, int Nsz, int Ksz,
    const float* __restrict__ target, const float* __restrict__ semb)
{
    __shared__ uint16_t lA[2][64 * 64];
    __shared__ uint16_t lB[2][64 * 64];
    const int t = threadIdx.x;
    const int lane = t & 63, w = t >> 6;
    const int wm = (w >> 1) * 32, wn = (w & 1) * 32;
    // XCD-chunked swizzle of the block id (bijective, nwg % 8 == 0 for all call sites)
    const int nwg = gridDim.x * gridDim.y;
    const int swz = xcd_swz(blockIdx.y * gridDim.x + blockIdx.x, nwg);
    const int m0 = (swz / gridDim.x) * 64, n0 = (swz % gridDim.x) * 64;
    const int l15 = lane & 15, l4 = lane >> 4;
    const int srow = lane >> 3, sseg = lane & 7;

    auto stage = [&](int buf, int k0) {
        const size_t bstride = KMOD ? 512 : (size_t)Ksz;
        const int bk0 = KMOD ? (k0 & 511) : k0;
        char* lab = (char*)lA[buf]; char* lbb = (char*)lB[buf];
#pragma unroll
        for (int i = 0; i < 2; ++i) {
            int row = w * 16 + i * 8 + srow;
            const char* ga = (const char*)A + ((size_t)(m0 + row) * Ksz + k0) * 2 + sseg * 16;
            __builtin_amdgcn_global_load_lds(AS1(ga), AS3(lab + (w * 16 + i * 8) * 128), 16, 0, 0);
            const char* gb = (const char*)Bw + ((size_t)(n0 + row) * bstride + bk0) * 2 + sseg * 16;
            __builtin_amdgcn_global_load_lds(AS1(gb), AS3(lbb + (w * 16 + i * 8) * 128), 16, 0, 0);
        }
    };

    f32x4 acc[2][2] = {};
    const int nk = Ksz >> 6;
    stage(0, 0);
    __syncthreads();
    for (int i = 0; i < nk; ++i) {
        if (i + 1 < nk) stage((i + 1) & 1, (i + 1) * 64);
        const char* lab = (const char*)lA[i & 1];
        const char* lbb = (const char*)lB[i & 1];
#pragma unroll
        for (int kf = 0; kf < 2; ++kf) {
            bfx8 af[2], bf2[2];
#pragma unroll
            for (int mf = 0; mf < 2; ++mf)
                af[mf] = *(const bfx8*)(lab + (wm + mf * 16 + l15) * 128 + kf * 64 + l4 * 16);
#pragma unroll
            for (int nf = 0; nf < 2; ++nf)
                bf2[nf] = *(const bfx8*)(lbb + (wn + nf * 16 + l15) * 128 + kf * 64 + l4 * 16);
#pragma unroll
            for (int mf = 0; mf < 2; ++mf)
#pragma unroll
                for (int nf = 0; nf < 2; ++nf)
                    acc[mf][nf] = __builtin_amdgcn_mfma_f32_16x16x32_bf16(af[mf], bf2[nf], acc[mf][nf], 0, 0, 0);
        }
        __syncthreads();
    }
    if (STATION) {
        // embedding epilogue: + bias + station_emb (index -1 if any target NaN), write bf16
#pragma unroll
        for (int mf = 0; mf < 2; ++mf)
#pragma unroll
            for (int r = 0; r < 4; ++r) {
                int row = m0 + wm + mf * 16 + l4 * 4 + r;
                int s = row & 1023;
                bool bad = false;
#pragma unroll
                for (int v = 0; v < 6; ++v) bad = bad || isnan(target[(size_t)row * 6 + v]);
                int sid = bad ? 1024 : s;
#pragma unroll
                for (int nf = 0; nf < 2; ++nf) {
                    int col = n0 + wn + nf * 16 + l15;
                    float val = acc[mf][nf][r] + bias[col] + semb[(size_t)sid * 512 + col];
                    ((uint16_t*)Cout)[(size_t)row * Nsz + col] = f2bf(val);
                }
            }
        return;
    }
#pragma unroll
    for (int mf = 0; mf < 2; ++mf)
#pragma unroll
        for (int nf = 0; nf < 2; ++nf)
#pragma unroll
            for (int r = 0; r < 4; ++r) {
                int row = m0 + wm + mf * 16 + l4 * 4 + r;
                int col = n0 + wn + nf * 16 + l15;
                float v = acc[mf][nf][r];
                if (BIAS) v += bias[col];
                if (SILU) v = v * sigmoidf_(v);
                if (OUTBF) ((uint16_t*)Cout)[(size_t)row * Nsz + col] = f2bf(v);
                else       ((float*)Cout)[(size_t)row * Nsz + col] = v;
            }
}

// ---------------- bf16 MFMA GEMM 128x128 tile, 2-phase pipelined (qkv GEMM) ----------------
// VT: blocks with n0 >= 1024 (the V third of the qkv projection) write their output
// TRANSPOSED directly to vt [b][h][dh][S] (C-fragment holds 4 consecutive s per thread
// at fixed dh -> one u16x4 store). Replaces the separate vtrans_k kernel.
template<int VT>
__global__ __launch_bounds__(256) void gemm128(const uint16_t* __restrict__ A,
    const uint16_t* __restrict__ Bw, uint16_t* __restrict__ Cout, int Nsz, int Ksz,
    uint16_t* __restrict__ vtout)
{
    __shared__ uint16_t lA[2][128 * 64];
    __shared__ uint16_t lB[2][128 * 64];
    const int t = threadIdx.x;
    const int lane = t & 63, w = t >> 6;
    const int wm = (w >> 1) * 64, wn = (w & 1) * 64;
    // XCD-chunked swizzle (bijective; grid 12x32 = 384, % 8 == 0)
    const int nwg = gridDim.x * gridDim.y;
    const int swz = xcd_swz(blockIdx.y * gridDim.x + blockIdx.x, nwg);
    const int m0 = (swz / gridDim.x) * 128, n0 = (swz % gridDim.x) * 128;
    const int l15 = lane & 15, l4 = lane >> 4;
    const int srow = lane >> 3, sseg = lane & 7;

    auto stage = [&](int buf, int k0) {
        char* lab = (char*)lA[buf]; char* lbb = (char*)lB[buf];
#pragma unroll
        for (int i = 0; i < 4; ++i) {
            int row = w * 32 + i * 8 + srow;
            const char* ga = (const char*)A + ((size_t)(m0 + row) * Ksz + k0) * 2 + sseg * 16;
            __builtin_amdgcn_global_load_lds(AS1(ga), AS3(lab + (w * 32 + i * 8) * 128), 16, 0, 0);
            const char* gb = (const char*)Bw + ((size_t)(n0 + row) * Ksz + k0) * 2 + sseg * 16;
            __builtin_amdgcn_global_load_lds(AS1(gb), AS3(lbb + (w * 32 + i * 8) * 128), 16, 0, 0);
        }
    };

    f32x4 acc[4][4] = {};
    const int nk = Ksz >> 6;
    stage(0, 0);
    __syncthreads();
    for (int i = 0; i < nk; ++i) {
        if (i + 1 < nk) stage((i + 1) & 1, (i + 1) * 64);
        const char* lab = (const char*)lA[i & 1];
        const char* lbb = (const char*)lB[i & 1];
#pragma unroll
        for (int kf = 0; kf < 2; ++kf) {
            bfx8 af[4], bf2[4];
#pragma unroll
            for (int mf = 0; mf < 4; ++mf)
                af[mf] = *(const bfx8*)(lab + (wm + mf * 16 + l15) * 128 + kf * 64 + l4 * 16);
#pragma unroll
            for (int nf = 0; nf < 4; ++nf)
                bf2[nf] = *(const bfx8*)(lbb + (wn + nf * 16 + l15) * 128 + kf * 64 + l4 * 16);
#pragma unroll
            for (int mf = 0; mf < 4; ++mf)
#pragma unroll
                for (int nf = 0; nf < 4; ++nf)
                    acc[mf][nf] = __builtin_amdgcn_mfma_f32_16x16x32_bf16(af[mf], bf2[nf], acc[mf][nf], 0, 0, 0);
        }
        __syncthreads();
    }
    if (VT && n0 >= 1024) {
        // V block: write transposed to vt [b*8+h][dh=64][S=1024]
#pragma unroll
        for (int mf = 0; mf < 4; ++mf)
#pragma unroll
            for (int nf = 0; nf < 4; ++nf) {
                int colv = n0 + wn + nf * 16 + l15 - 1024;
                int hh = colv >> 6, dh = colv & 63;
                int row = m0 + wm + mf * 16 + l4 * 4;
                int b = row >> 10, s = row & 1023;
                u16x4 ov;
#pragma unroll
                for (int r = 0; r < 4; ++r) ov[r] = f2bf(acc[mf][nf][r]);
                *(u16x4*)(vtout + (size_t)((b * 8 + hh) * 64 + dh) * 1024 + s) = ov;
            }
        return;
    }
#pragma unroll
    for (int mf = 0; mf < 4; ++mf)
#pragma unroll
        for (int nf = 0; nf < 4; ++nf)
#pragma unroll
            for (int r = 0; r < 4; ++r) {
                int row = m0 + wm + mf * 16 + l4 * 4 + r;
                int col = n0 + wn + nf * 16 + l15;
                Cout[(size_t)row * Nsz + col] = f2bf(acc[mf][nf][r]);
            }
}

// ---------------- fused attention: batch-softmax in-register, K/V LDS-staged ----------------
// Block = 4 waves = 2 q-subtiles x 2 k-quarters (QBLK=32). Each k-quarter pair stages its
// own 32-k K/V tile into its 32KB LDS half (single-buffered, 2-barrier loop); both q-waves
// of the pair read it. Wave holds S^T for ALL 4 batches -> thread-local batch softmax;
// PV = mfma(V^T, P) with consistent k-permutation (HW-verified R6-R14). k-quarter partials
// combine via padded LDS; kq=0 waves store. Grid 512 (8h x 32qt x 2ks), 64KB LDS ->
// 2 blocks/CU. h = bid&7 pins each head's K/V to one XCD's L2 (round-robin dispatch).
__global__ __launch_bounds__(256, 2) void attn_k(const uint16_t* __restrict__ qkv,
    const uint16_t* __restrict__ vt, uint16_t* __restrict__ o16)
{
    __shared__ __align__(16) char lds[2][32768];   // [kq][ K 16KB | V 16KB ]
    const int t = threadIdx.x;
    const int lane = t & 63, w = t >> 6;
    const int l15 = lane & 15, l4 = lane >> 4;
    const int qsub = w & 1, kq = w >> 1;
    const int bid = blockIdx.x;
    const int h = bid & 7, qt = (bid >> 3) & 31, ks = bid >> 8;
    const int q0 = qt * 32 + qsub * 16;

    bfx8 qa[4][2];
#pragma unroll
    for (int b = 0; b < 4; ++b)
#pragma unroll
        for (int kf = 0; kf < 2; ++kf)
            qa[b][kf] = *(const bfx8*)(qkv + (size_t)(b * 1024 + q0 + l15) * 1536 + h * 64 + kf * 32 + l4 * 8);

    char* Kb = lds[kq];
    char* Vb = lds[kq] + 16384;

    auto stage = [&](int k0) {
#pragma unroll
        for (int j = 0; j < 8; ++j) {
            const int i = qsub * 8 + j;
            {   // K instr i: rows 8i..8i+7
                int rho = i * 8 + (lane >> 3);
                int cd = (lane & 7) ^ (rho & 7);
                int b = rho >> 5, kl = rho & 31;
                const uint16_t* g = qkv + (size_t)(b * 1024 + k0 + kl) * 1536 + 512 + h * 64 + cd * 8;
                __builtin_amdgcn_global_load_lds(AS1(g), AS3(Kb + i * 1024), 16, 0, 0);
            }
            {   // V instr i: rows 16i..16i+15
                int row = i * 16 + (lane >> 2);
                int cd = (lane & 3) ^ (row & 3);
                int b = row >> 6, d = row & 63;
                const uint16_t* g = vt + (size_t)((b * 8 + h) * 64 + d) * 1024 + k0 + cd * 8;
                __builtin_amdgcn_global_load_lds(AS1(g), AS3(Vb + i * 1024), 16, 0, 0);
            }
        }
    };

    f32x4 oacc[4][4] = {};           // [b][m]: O^T[d = m*16 + 4*l4 + r][q0 + l15]
    const int kbase = ks * 512 + kq * 256;
    for (int tt = 0; tt < 8; ++tt) {
        stage(kbase + tt * 32);
        __syncthreads();
        f32x4 sacc[4][2] = {};
#pragma unroll
        for (int b = 0; b < 4; ++b)
#pragma unroll
            for (int kt = 0; kt < 2; ++kt) {
                int rho = b * 32 + kt * 16 + l15;
#pragma unroll
                for (int kf = 0; kf < 2; ++kf) {
                    int slot = (kf * 4 + l4) ^ (rho & 7);
                    bfx8 kb = *(const bfx8*)(Kb + rho * 128 + slot * 16);
                    sacc[b][kt] = __builtin_amdgcn_mfma_f32_16x16x32_bf16(kb, qa[b][kf], sacc[b][kt], 0, 0, 0);
                }
            }
        float p[2][4][4];            // [kt][b][r]
#pragma unroll
        for (int kt = 0; kt < 2; ++kt)
#pragma unroll
            for (int r = 0; r < 4; ++r) {
                float s0 = sacc[0][kt][r], s1 = sacc[1][kt][r];
                float s2 = sacc[2][kt][r], s3 = sacc[3][kt][r];
                float mx = fmaxf(fmaxf(s0, s1), fmaxf(s2, s3));
                float e0 = __expf((s0 - mx) * 0.125f);
                float e1 = __expf((s1 - mx) * 0.125f);
                float e2 = __expf((s2 - mx) * 0.125f);
                float e3 = __expf((s3 - mx) * 0.125f);
                float inv = frcp(e0 + e1 + e2 + e3);
                p[kt][0][r] = e0 * inv; p[kt][1][r] = e1 * inv;
                p[kt][2][r] = e2 * inv; p[kt][3][r] = e3 * inv;
            }
#pragma unroll
        for (int b = 0; b < 4; ++b) {
            union { uint32_t u[4]; bfx8 v; } pf;
            pf.u[0] = cvtpk(p[0][b][0], p[0][b][1]);
            pf.u[1] = cvtpk(p[0][b][2], p[0][b][3]);
            pf.u[2] = cvtpk(p[1][b][0], p[1][b][1]);
            pf.u[3] = cvtpk(p[1][b][2], p[1][b][3]);
#pragma unroll
            for (int m = 0; m < 4; ++m) {
                int row = b * 64 + m * 16 + l15;
                int c0 = ((l4 >> 1)) ^ (row & 3);          // kt=0 chunk
                int c1 = (2 + (l4 >> 1)) ^ (row & 3);      // kt=1 chunk
                u16x4 v0 = *(const u16x4*)(Vb + row * 64 + c0 * 16 + (l4 & 1) * 8);
                u16x4 v1 = *(const u16x4*)(Vb + row * 64 + c1 * 16 + (l4 & 1) * 8);
                union { u16x8 u; bfx8 v; } vf;
                vf.u = __builtin_shufflevector(v0, v1, 0, 1, 2, 3, 4, 5, 6, 7);
                oacc[b][m] = __builtin_amdgcn_mfma_f32_16x16x32_bf16(vf.v, pf.v, oacc[b][m], 0, 0, 0);
            }
        }
        __syncthreads();
    }
    // combine the two k-quarters (padded LDS: stride 68 floats)
    float* cb = (float*)lds;
    if (kq == 1) {
#pragma unroll
        for (int b = 0; b < 4; ++b)
#pragma unroll
            for (int m = 0; m < 4; ++m)
                *(f32x4*)&cb[(qsub * 64 + lane) * 68 + (b * 4 + m) * 4] = oacc[b][m];
    }
    __syncthreads();
    if (kq == 0) {
#pragma unroll
        for (int b = 0; b < 4; ++b)
#pragma unroll
            for (int m = 0; m < 4; ++m) {
                f32x4 v = oacc[b][m] + *(const f32x4*)&cb[(qsub * 64 + lane) * 68 + (b * 4 + m) * 4];
                u16x4 ov;
#pragma unroll
                for (int r = 0; r < 4; ++r) ov[r] = f2bf(v[r]);
                *(u16x4*)(o16 + (size_t)(b * 1024 + q0 + l15) * 1024 + ks * 512 + h * 64 + m * 16 + 4 * l4) = ov;
            }
    }
}

// ---------------- fused  ln_attn -> silu -> ln1  (one wave per row) ----------------
__global__ __launch_bounds__(64) void ln_fuse_k(const float* __restrict__ in,
    const float* __restrict__ g1, const float* __restrict__ b1,
    const float* __restrict__ g2, const float* __restrict__ b2,
    float* __restrict__ h32, uint16_t* __restrict__ h16)
{
    const int row = blockIdx.x, lane = threadIdx.x;
    const float* p = in + (size_t)row * 512 + lane * 8;
    f32x4 a = *(const f32x4*)p, bvec = *(const f32x4*)(p + 4);
    float x[8] = {a[0], a[1], a[2], a[3], bvec[0], bvec[1], bvec[2], bvec[3]};
    float sum = 0.f, sq = 0.f;
#pragma unroll
    for (int i = 0; i < 8; ++i) { sum += x[i]; sq += x[i] * x[i]; }
    for (int m = 32; m; m >>= 1) { sum += __shfl_xor(sum, m); sq += __shfl_xor(sq, m); }
    float mu = sum * (1.f / 512.f);
    float rs = rsqrtf(sq * (1.f / 512.f) - mu * mu + 1e-5f);
    float y[8]; float s2 = 0.f, q2 = 0.f;
#pragma unroll
    for (int i = 0; i < 8; ++i) {
        int c = lane * 8 + i;
        float v = (x[i] - mu) * rs * g1[c] + b1[c];
        v = v * sigmoidf_(v);
        y[i] = v; s2 += v; q2 += v * v;
    }
    for (int m = 32; m; m >>= 1) { s2 += __shfl_xor(s2, m); q2 += __shfl_xor(q2, m); }
    float mu2 = s2 * (1.f / 512.f);
    float rs2 = rsqrtf(q2 * (1.f / 512.f) - mu2 * mu2 + 1e-5f);
#pragma unroll
    for (int i = 0; i < 8; ++i) {
        int c = lane * 8 + i;
        float v = (y[i] - mu2) * rs2 * g2[c] + b2[c];
        h32[(size_t)row * 512 + c] = v;
        h16[(size_t)row * 512 + c] = f2bf(v);
    }
}

// ---------------- x16 = ln2(f + h); LAST layer also computes the regression head ----------------
template<int LAST>
__global__ __launch_bounds__(64) void ln_res_k(const float* __restrict__ f, const float* __restrict__ hres,
    const float* __restrict__ g, const float* __restrict__ bb, uint16_t* __restrict__ x16,
    const float* __restrict__ regW, const float* __restrict__ regb, float* __restrict__ out)
{
    const int row = blockIdx.x, lane = threadIdx.x;
    const size_t base = (size_t)row * 512 + lane * 8;
    f32x4 a = *(const f32x4*)(f + base), b2v = *(const f32x4*)(f + base + 4);
    f32x4 ha = *(const f32x4*)(hres + base), hb = *(const f32x4*)(hres + base + 4);
    float x[8] = {a[0] + ha[0], a[1] + ha[1], a[2] + ha[2], a[3] + ha[3],
                  b2v[0] + hb[0], b2v[1] + hb[1], b2v[2] + hb[2], b2v[3] + hb[3]};
    float sum = 0.f, sq = 0.f;
#pragma unroll
    for (int i = 0; i < 8; ++i) { sum += x[i]; sq += x[i] * x[i]; }
    for (int m = 32; m; m >>= 1) { sum += __shfl_xor(sum, m); sq += __shfl_xor(sq, m); }
    float mu = sum * (1.f / 512.f);
    float rs = rsqrtf(sq * (1.f / 512.f) - mu * mu + 1e-5f);
    float v[8];
#pragma unroll
    for (int i = 0; i < 8; ++i) {
        int c = lane * 8 + i;
        v[i] = (x[i] - mu) * rs * g[c] + bb[c];
    }
    if (!LAST) {
#pragma unroll
        for (int i = 0; i < 8; ++i) x16[base + i] = f2bf(v[i]);
    } else {
        float acc[18];
#pragma unroll
        for (int j = 0; j < 18; ++j) acc[j] = 0.f;
#pragma unroll
        for (int i = 0; i < 8; ++i) {
            const float* wr = regW + (size_t)(lane * 8 + i) * 18;
#pragma unroll
            for (int j = 0; j < 18; ++j) acc[j] += v[i] * wr[j];
        }
#pragma unroll
        for (int j = 0; j < 18; ++j) {
            acc[j] += __shfl_xor(acc[j], 1);
            acc[j] += __shfl_xor(acc[j], 2);
            acc[j] += __shfl_xor(acc[j], 4);
            acc[j] += __shfl_xor(acc[j], 8);
            acc[j] += __shfl_xor(acc[j], 16);
            acc[j] += __shfl_xor(acc[j], 32);
        }
        if (lane == 0) {
#pragma unroll
            for (int j = 0; j < 18; ++j)
                out[(size_t)row * 18 + j] = acc[j] + regb[j];
        }
    }
}

// ---------------- launch ----------------
extern "C" void kernel_launch(void* const* d_in, const int* in_sizes, int n_in,
                              void* d_out, int out_size, void* d_ws, size_t ws_size,
                              hipStream_t stream)
{
    const float* features = (const float*)d_in[0];
    const float* target   = (const float*)d_in[1];
    const float* emb_W    = (const float*)d_in[4];
    const float* emb_b    = (const float*)d_in[5];
    const float* station  = (const float*)d_in[6];
    const float* Wq   = (const float*)d_in[7];
    const float* Wk   = (const float*)d_in[8];
    const float* Wv   = (const float*)d_in[9];
    const float* Wo   = (const float*)d_in[10];
    const float* attn_b = (const float*)d_in[11];
    const float* lng  = (const float*)d_in[12];
    const float* lnb  = (const float*)d_in[13];
    const float* W1   = (const float*)d_in[14];
    const float* b1   = (const float*)d_in[15];
    const float* W2   = (const float*)d_in[16];
    const float* b2   = (const float*)d_in[17];
    const float* ln1g = (const float*)d_in[18];
    const float* ln1b = (const float*)d_in[19];
    const float* ln2g = (const float*)d_in[20];
    const float* ln2b = (const float*)d_in[21];
    const float* regW = (const float*)d_in[22];
    const float* regb = (const float*)d_in[23];
    float* out = (float*)d_out;

    const size_t NEEDED = 73531392;
    if (ws_size < NEEDED) return;   // fail visibly (output stays poisoned) rather than corrupt

    char* ws = (char*)d_ws;
    uint16_t* wt   = (uint16_t*)(ws);             // 19,005,440 B bf16 weight arena
    uint16_t* x16  = (uint16_t*)(ws + 19005440);  // 4 MB
    uint16_t* qkv  = (uint16_t*)(ws + 23199744);  // 12 MB
    uint16_t* vt   = (uint16_t*)(ws + 35782656);  // 4 MB
    uint16_t* o16  = (uint16_t*)(ws + 39976960);  // 8 MB  [4096][1024] split-O
    float*    t32  = (float*)(ws + 48365568);     // 8 MB
    float*    h32  = (float*)(ws + 56754176);     // 8 MB
    uint16_t* h16  = (uint16_t*)(ws + 65142784);  // 4 MB
    uint16_t* f16  = (uint16_t*)(ws + 69337088);  // 4 MB
    uint16_t* fm16 = (uint16_t*)(ws + 56754176);  // 1 MB, aliases h32 (dead until layer 0 ln_fuse)

    wconv_k<<<dim3(8, 8, 37), 256, 0, stream>>>(Wq, Wk, Wv, Wo, W1, W2, emb_W, wt);
    fmean_k<<<dim3(2048), 256, 0, stream>>>(features, fm16);
    // embedding GEMM with fused bias + station embedding (+NaN gating), writes x16 directly
    gemm64<1, 0, 1, 0, 1><<<dim3(8, 64), 256, 0, stream>>>(fm16, wt + 9437184u, emb_b, x16, 4096, 512, 128, target, station);

    for (int l = 0; l < 6; ++l) {
        // qkv projection; V third written transposed directly to vt (fused vtrans)
        gemm128<1><<<dim3(12, 32), 256, 0, stream>>>(x16, wt + (size_t)l * 786432u, qkv, 1536, 512, vt);
        attn_k<<<dim3(512), 256, 0, stream>>>(qkv, vt, o16);
        gemm64<1, 0, 0, 1, 0><<<dim3(8, 64), 256, 0, stream>>>(o16, wt + 4718592u + (size_t)l * 262144u, attn_b + l * 512, t32, 4096, 512, 1024, nullptr, nullptr);
        ln_fuse_k<<<dim3(4096), 64, 0, stream>>>(t32, lng + l * 512, lnb + l * 512, ln1g + l * 512, ln1b + l * 512, h32, h16);
        gemm64<1, 1, 1, 0, 0><<<dim3(8, 64), 256, 0, stream>>>(h16, wt + 6291456u + (size_t)l * 262144u, b1 + l * 512, f16, 4096, 512, 512, nullptr, nullptr);
        gemm64<1, 0, 0, 0, 0><<<dim3(8, 64), 256, 0, stream>>>(f16, wt + 7864320u + (size_t)l * 262144u, b2 + l * 512, t32, 4096, 512, 512, nullptr, nullptr);
        if (l < 5)
            ln_res_k<0><<<dim3(4096), 64, 0, stream>>>(t32, h32, ln2g + l * 512, ln2b + l * 512, x16, regW, regb, out);
        else
            ln_res_k<1><<<dim3(4096), 64, 0, stream>>>(t32, h32, ln2g + l * 512, ln2b + l * 512, x16, regW, regb, out);
    }
}

// Round 16
// 608.525 us; speedup vs baseline: 1.0438x; 1.0438x over previous
//
#include <hip/hip_runtime.h>
#include <stdint.h>

// ---------------- types ----------------
typedef float   f32x4 __attribute__((ext_vector_type(4)));
typedef float   f32x2 __attribute__((ext_vector_type(2)));
typedef __bf16  bfx8  __attribute__((ext_vector_type(8)));
typedef uint16_t u16x8 __attribute__((ext_vector_type(8)));
typedef uint16_t u16x4 __attribute__((ext_vector_type(4)));

#define AS1(p) ((__attribute__((address_space(1))) void*)(p))
#define AS3(p) ((__attribute__((address_space(3))) void*)(p))

__device__ __forceinline__ uint16_t f2bf(float f) {
    union { float f; uint32_t u; } c; c.f = f;
    uint32_t u = c.u;
    return (uint16_t)((u + 0x7FFFu + ((u >> 16) & 1u)) >> 16);
}
__device__ __forceinline__ float bf2f(uint16_t v) {
    union { uint32_t u; float f; } c; c.u = ((uint32_t)v) << 16; return c.f;
}
__device__ __forceinline__ float sigmoidf_(float x) { return 1.0f / (1.0f + __expf(-x)); }
__device__ __forceinline__ float frcp(float x) { float r; asm("v_rcp_f32 %0, %1" : "=v"(r) : "v"(x)); return r; }
__device__ __forceinline__ uint32_t cvtpk(float lo, float hi) {
    uint32_t r; asm("v_cvt_pk_bf16_f32 %0, %1, %2" : "=v"(r) : "v"(lo), "v"(hi)); return r;
}

// ---------------- weight convert+transpose: fp32 [K][N] -> bf16 [N][K] ----------------
// arena layout (uint16 units):
//   wqkv: [L][1536][512]   @ 0         (q rows 0..511, k 512..1023, v 1024..1535)
//   wo  : [L][512][512]    @ 4718592
//   w1  : [L][512][512]    @ 6291456
//   w2  : [L][512][512]    @ 7864320
//   wemb: [512][128]       @ 9437184
__global__ __launch_bounds__(256) void wconv_k(
    const float* __restrict__ Wq, const float* __restrict__ Wk, const float* __restrict__ Wv,
    const float* __restrict__ Wo, const float* __restrict__ W1, const float* __restrict__ W2,
    const float* __restrict__ Wemb, uint16_t* __restrict__ arena)
{
    __shared__ uint16_t tl[64][65];
    const int z = blockIdx.z;
    const float* in; uint16_t* out; int K, N;
    if (z < 36) {
        const int type = z / 6, l = z % 6;
        const float* bases[6] = {Wq, Wk, Wv, Wo, W1, W2};
        in = bases[type] + (size_t)l * 512 * 512;
        K = 512; N = 512;
        if (type < 3) out = arena + (size_t)l * 786432u + (size_t)type * 262144u;
        else          out = arena + 4718592u + (size_t)(type - 3) * 1572864u + (size_t)l * 262144u;
    } else {
        if (blockIdx.y >= 2) return;      // K=128 -> only 2 k-tiles
        in = Wemb; K = 128; N = 512;
        out = arena + 9437184u;
    }
    const int n0 = blockIdx.x * 64, k0 = blockIdx.y * 64;
    const int t = threadIdx.x, r = t >> 2, seg = t & 3;
    const float* src = in + (size_t)(k0 + r) * N + n0 + seg * 16;
#pragma unroll
    for (int v2 = 0; v2 < 4; ++v2) {
        f32x4 d = *(const f32x4*)(src + v2 * 4);
#pragma unroll
        for (int j = 0; j < 4; ++j) tl[r][seg * 16 + v2 * 4 + j] = f2bf(d[j]);
    }
    __syncthreads();
    u16x8 o0, o1;
#pragma unroll
    for (int j = 0; j < 8; ++j) { o0[j] = tl[seg * 16 + j][r]; o1[j] = tl[seg * 16 + 8 + j][r]; }
    uint16_t* dst = out + (size_t)(n0 + r) * K + k0 + seg * 16;
    *(u16x8*)dst = o0; *(u16x8*)(dst + 8) = o1;
}

// ---------------- mean over ensemble M=10: features [B,M,S,F] -> bf16 [T][F] ----------------
__global__ __launch_bounds__(256) void fmean_k(const float* __restrict__ feat, uint16_t* __restrict__ fm)
{
    int id = blockIdx.x * 256 + threadIdx.x;      // 0 .. 4096*128-1
    int f = id & 127, row = id >> 7;              // row = b*1024+s
    int b = row >> 10, s = row & 1023;
    float acc = 0.f;
#pragma unroll
    for (int m = 0; m < 10; ++m)
        acc += feat[(size_t)((b * 10 + m) * 1024 + s) * 128 + f];
    fm[id] = f2bf(acc * 0.1f);
}

// ---------------- bf16 MFMA GEMM 64x64 tile, 2-phase pipelined ----------------
// C[M,N] = A[M,K] @ Bw^T. Bw is [N][Kb], Kb = KMOD ? 512 : Ksz (KMOD: logical K wraps
// mod 512 -> Wo reuse for split-O attention output by linearity).
// STATION: epilogue adds station embedding (NaN-gated per row) and writes bf16 x16
// (fuses the old station_k kernel into the embedding GEMM).
template<int BIAS, int SILU, int OUTBF, int KMOD, int STATION>
__global__ __launch_bounds__(256) void gemm64(const uint16_t* __restrict__ A,
    const uint16_t* __restrict__ Bw, const float* __restrict__ bias,
    void* __restrict__ Cout, int Msz, int Nsz, int Ksz,
    const float* __restrict__ target, const float* __restrict__ semb)
{
    __shared__ uint16_t lA[2][64 * 64];
    __shared__ uint16_t lB[2][64 * 64];
    const int t = threadIdx.x;
    const int lane = t & 63, w = t >> 6;
    const int wm = (w >> 1) * 32, wn = (w & 1) * 32;
    const int m0 = blockIdx.y * 64, n0 = blockIdx.x * 64;
    const int l15 = lane & 15, l4 = lane >> 4;
    const int srow = lane >> 3, sseg = lane & 7;

    auto stage = [&](int buf, int k0) {
        const size_t bstride = KMOD ? 512 : (size_t)Ksz;
        const int bk0 = KMOD ? (k0 & 511) : k0;
        char* lab = (char*)lA[buf]; char* lbb = (char*)lB[buf];
#pragma unroll
        for (int i = 0; i < 2; ++i) {
            int row = w * 16 + i * 8 + srow;
            const char* ga = (const char*)A + ((size_t)(m0 + row) * Ksz + k0) * 2 + sseg * 16;
            __builtin_amdgcn_global_load_lds(AS1(ga), AS3(lab + (w * 16 + i * 8) * 128), 16, 0, 0);
            const char* gb = (const char*)Bw + ((size_t)(n0 + row) * bstride + bk0) * 2 + sseg * 16;
            __builtin_amdgcn_global_load_lds(AS1(gb), AS3(lbb + (w * 16 + i * 8) * 128), 16, 0, 0);
        }
    };

    f32x4 acc[2][2] = {};
    const int nk = Ksz >> 6;
    stage(0, 0);
    __syncthreads();
    for (int i = 0; i < nk; ++i) {
        if (i + 1 < nk) stage((i + 1) & 1, (i + 1) * 64);
        const char* lab = (const char*)lA[i & 1];
        const char* lbb = (const char*)lB[i & 1];
#pragma unroll
        for (int kf = 0; kf < 2; ++kf) {
            bfx8 af[2], bf2[2];
#pragma unroll
            for (int mf = 0; mf < 2; ++mf)
                af[mf] = *(const bfx8*)(lab + (wm + mf * 16 + l15) * 128 + kf * 64 + l4 * 16);
#pragma unroll
            for (int nf = 0; nf < 2; ++nf)
                bf2[nf] = *(const bfx8*)(lbb + (wn + nf * 16 + l15) * 128 + kf * 64 + l4 * 16);
#pragma unroll
            for (int mf = 0; mf < 2; ++mf)
#pragma unroll
                for (int nf = 0; nf < 2; ++nf)
                    acc[mf][nf] = __builtin_amdgcn_mfma_f32_16x16x32_bf16(af[mf], bf2[nf], acc[mf][nf], 0, 0, 0);
        }
        __syncthreads();
    }
    if (STATION) {
        // embedding epilogue: + bias + station_emb (index -1 if any target NaN), write bf16
#pragma unroll
        for (int mf = 0; mf < 2; ++mf)
#pragma unroll
            for (int r = 0; r < 4; ++r) {
                int row = m0 + wm + mf * 16 + l4 * 4 + r;
                int s = row & 1023;
                bool bad = false;
#pragma unroll
                for (int v = 0; v < 6; ++v) bad = bad || isnan(target[(size_t)row * 6 + v]);
                int sid = bad ? 1024 : s;
#pragma unroll
                for (int nf = 0; nf < 2; ++nf) {
                    int col = n0 + wn + nf * 16 + l15;
                    float val = acc[mf][nf][r] + bias[col] + semb[(size_t)sid * 512 + col];
                    ((uint16_t*)Cout)[(size_t)row * Nsz + col] = f2bf(val);
                }
            }
        return;
    }
#pragma unroll
    for (int mf = 0; mf < 2; ++mf)
#pragma unroll
        for (int nf = 0; nf < 2; ++nf)
#pragma unroll
            for (int r = 0; r < 4; ++r) {
                int row = m0 + wm + mf * 16 + l4 * 4 + r;
                int col = n0 + wn + nf * 16 + l15;
                float v = acc[mf][nf][r];
                if (BIAS) v += bias[col];
                if (SILU) v = v * sigmoidf_(v);
                if (OUTBF) ((uint16_t*)Cout)[(size_t)row * Nsz + col] = f2bf(v);
                else       ((float*)Cout)[(size_t)row * Nsz + col] = v;
            }
}

// ---------------- bf16 MFMA GEMM 128x128 tile, 2-phase pipelined (qkv GEMM) ----------------
// VT: blocks with n0 >= 1024 (the V third of the qkv projection) write their output
// TRANSPOSED directly to vt [b][h][dh][S] (C-fragment holds 4 consecutive s per thread
// at fixed dh -> one u16x4 store). Replaces the separate vtrans_k kernel.
template<int VT>
__global__ __launch_bounds__(256) void gemm128(const uint16_t* __restrict__ A,
    const uint16_t* __restrict__ Bw, uint16_t* __restrict__ Cout, int Nsz, int Ksz,
    uint16_t* __restrict__ vtout)
{
    __shared__ uint16_t lA[2][128 * 64];
    __shared__ uint16_t lB[2][128 * 64];
    const int t = threadIdx.x;
    const int lane = t & 63, w = t >> 6;
    const int wm = (w >> 1) * 64, wn = (w & 1) * 64;
    const int m0 = blockIdx.y * 128, n0 = blockIdx.x * 128;
    const int l15 = lane & 15, l4 = lane >> 4;
    const int srow = lane >> 3, sseg = lane & 7;

    auto stage = [&](int buf, int k0) {
        char* lab = (char*)lA[buf]; char* lbb = (char*)lB[buf];
#pragma unroll
        for (int i = 0; i < 4; ++i) {
            int row = w * 32 + i * 8 + srow;
            const char* ga = (const char*)A + ((size_t)(m0 + row) * Ksz + k0) * 2 + sseg * 16;
            __builtin_amdgcn_global_load_lds(AS1(ga), AS3(lab + (w * 32 + i * 8) * 128), 16, 0, 0);
            const char* gb = (const char*)Bw + ((size_t)(n0 + row) * Ksz + k0) * 2 + sseg * 16;
            __builtin_amdgcn_global_load_lds(AS1(gb), AS3(lbb + (w * 32 + i * 8) * 128), 16, 0, 0);
        }
    };

    f32x4 acc[4][4] = {};
    const int nk = Ksz >> 6;
    stage(0, 0);
    __syncthreads();
    for (int i = 0; i < nk; ++i) {
        if (i + 1 < nk) stage((i + 1) & 1, (i + 1) * 64);
        const char* lab = (const char*)lA[i & 1];
        const char* lbb = (const char*)lB[i & 1];
#pragma unroll
        for (int kf = 0; kf < 2; ++kf) {
            bfx8 af[4], bf2[4];
#pragma unroll
            for (int mf = 0; mf < 4; ++mf)
                af[mf] = *(const bfx8*)(lab + (wm + mf * 16 + l15) * 128 + kf * 64 + l4 * 16);
#pragma unroll
            for (int nf = 0; nf < 4; ++nf)
                bf2[nf] = *(const bfx8*)(lbb + (wn + nf * 16 + l15) * 128 + kf * 64 + l4 * 16);
#pragma unroll
            for (int mf = 0; mf < 4; ++mf)
#pragma unroll
                for (int nf = 0; nf < 4; ++nf)
                    acc[mf][nf] = __builtin_amdgcn_mfma_f32_16x16x32_bf16(af[mf], bf2[nf], acc[mf][nf], 0, 0, 0);
        }
        __syncthreads();
    }
    if (VT && n0 >= 1024) {
        // V block: write transposed to vt [b*8+h][dh=64][S=1024]
#pragma unroll
        for (int mf = 0; mf < 4; ++mf)
#pragma unroll
            for (int nf = 0; nf < 4; ++nf) {
                int colv = n0 + wn + nf * 16 + l15 - 1024;
                int hh = colv >> 6, dh = colv & 63;
                int row = m0 + wm + mf * 16 + l4 * 4;
                int b = row >> 10, s = row & 1023;
                u16x4 ov;
#pragma unroll
                for (int r = 0; r < 4; ++r) ov[r] = f2bf(acc[mf][nf][r]);
                *(u16x4*)(vtout + (size_t)((b * 8 + hh) * 64 + dh) * 1024 + s) = ov;
            }
        return;
    }
#pragma unroll
    for (int mf = 0; mf < 4; ++mf)
#pragma unroll
        for (int nf = 0; nf < 4; ++nf)
#pragma unroll
            for (int r = 0; r < 4; ++r) {
                int row = m0 + wm + mf * 16 + l4 * 4 + r;
                int col = n0 + wn + nf * 16 + l15;
                Cout[(size_t)row * Nsz + col] = f2bf(acc[mf][nf][r]);
            }
}

// ---------------- fused attention: batch-softmax in-register, K/V LDS-staged ----------------
// Block = 4 waves = 2 q-subtiles x 2 k-quarters (QBLK=32). Each k-quarter pair stages its
// own 32-k K/V tile into its 32KB LDS half (single-buffered, 2-barrier loop); both q-waves
// of the pair read it. Wave holds S^T for ALL 4 batches -> thread-local batch softmax;
// PV = mfma(V^T, P) with consistent k-permutation (HW-verified R6-R15). k-quarter partials
// combine via padded LDS; kq=0 waves store. Grid 512 (8h x 32qt x 2ks), 64KB LDS ->
// 2 blocks/CU. h = bid&7 pins each head's K/V to one XCD's L2 (round-robin dispatch).
__global__ __launch_bounds__(256, 2) void attn_k(const uint16_t* __restrict__ qkv,
    const uint16_t* __restrict__ vt, uint16_t* __restrict__ o16)
{
    __shared__ __align__(16) char lds[2][32768];   // [kq][ K 16KB | V 16KB ]
    const int t = threadIdx.x;
    const int lane = t & 63, w = t >> 6;
    const int l15 = lane & 15, l4 = lane >> 4;
    const int qsub = w & 1, kq = w >> 1;
    const int bid = blockIdx.x;
    const int h = bid & 7, qt = (bid >> 3) & 31, ks = bid >> 8;
    const int q0 = qt * 32 + qsub * 16;

    bfx8 qa[4][2];
#pragma unroll
    for (int b = 0; b < 4; ++b)
#pragma unroll
        for (int kf = 0; kf < 2; ++kf)
            qa[b][kf] = *(const bfx8*)(qkv + (size_t)(b * 1024 + q0 + l15) * 1536 + h * 64 + kf * 32 + l4 * 8);

    char* Kb = lds[kq];
    char* Vb = lds[kq] + 16384;

    auto stage = [&](int k0) {
#pragma unroll
        for (int j = 0; j < 8; ++j) {
            const int i = qsub * 8 + j;
            {   // K instr i: rows 8i..8i+7
                int rho = i * 8 + (lane >> 3);
                int cd = (lane & 7) ^ (rho & 7);
                int b = rho >> 5, kl = rho & 31;
                const uint16_t* g = qkv + (size_t)(b * 1024 + k0 + kl) * 1536 + 512 + h * 64 + cd * 8;
                __builtin_amdgcn_global_load_lds(AS1(g), AS3(Kb + i * 1024), 16, 0, 0);
            }
            {   // V instr i: rows 16i..16i+15
                int row = i * 16 + (lane >> 2);
                int cd = (lane & 3) ^ (row & 3);
                int b = row >> 6, d = row & 63;
                const uint16_t* g = vt + (size_t)((b * 8 + h) * 64 + d) * 1024 + k0 + cd * 8;
                __builtin_amdgcn_global_load_lds(AS1(g), AS3(Vb + i * 1024), 16, 0, 0);
            }
        }
    };

    f32x4 oacc[4][4] = {};           // [b][m]: O^T[d = m*16 + 4*l4 + r][q0 + l15]
    const int kbase = ks * 512 + kq * 256;
    for (int tt = 0; tt < 8; ++tt) {
        stage(kbase + tt * 32);
        __syncthreads();
        f32x4 sacc[4][2] = {};
#pragma unroll
        for (int b = 0; b < 4; ++b)
#pragma unroll
            for (int kt = 0; kt < 2; ++kt) {
                int rho = b * 32 + kt * 16 + l15;
#pragma unroll
                for (int kf = 0; kf < 2; ++kf) {
                    int slot = (kf * 4 + l4) ^ (rho & 7);
                    bfx8 kb = *(const bfx8*)(Kb + rho * 128 + slot * 16);
                    sacc[b][kt] = __builtin_amdgcn_mfma_f32_16x16x32_bf16(kb, qa[b][kf], sacc[b][kt], 0, 0, 0);
                }
            }
        float p[2][4][4];            // [kt][b][r]
#pragma unroll
        for (int kt = 0; kt < 2; ++kt)
#pragma unroll
            for (int r = 0; r < 4; ++r) {
                float s0 = sacc[0][kt][r], s1 = sacc[1][kt][r];
                float s2 = sacc[2][kt][r], s3 = sacc[3][kt][r];
                float mx = fmaxf(fmaxf(s0, s1), fmaxf(s2, s3));
                float e0 = __expf((s0 - mx) * 0.125f);
                float e1 = __expf((s1 - mx) * 0.125f);
                float e2 = __expf((s2 - mx) * 0.125f);
                float e3 = __expf((s3 - mx) * 0.125f);
                float inv = frcp(e0 + e1 + e2 + e3);
                p[kt][0][r] = e0 * inv; p[kt][1][r] = e1 * inv;
                p[kt][2][r] = e2 * inv; p[kt][3][r] = e3 * inv;
            }
#pragma unroll
        for (int b = 0; b < 4; ++b) {
            union { uint32_t u[4]; bfx8 v; } pf;
            pf.u[0] = cvtpk(p[0][b][0], p[0][b][1]);
            pf.u[1] = cvtpk(p[0][b][2], p[0][b][3]);
            pf.u[2] = cvtpk(p[1][b][0], p[1][b][1]);
            pf.u[3] = cvtpk(p[1][b][2], p[1][b][3]);
#pragma unroll
            for (int m = 0; m < 4; ++m) {
                int row = b * 64 + m * 16 + l15;
                int c0 = ((l4 >> 1)) ^ (row & 3);          // kt=0 chunk
                int c1 = (2 + (l4 >> 1)) ^ (row & 3);      // kt=1 chunk
                u16x4 v0 = *(const u16x4*)(Vb + row * 64 + c0 * 16 + (l4 & 1) * 8);
                u16x4 v1 = *(const u16x4*)(Vb + row * 64 + c1 * 16 + (l4 & 1) * 8);
                union { u16x8 u; bfx8 v; } vf;
                vf.u = __builtin_shufflevector(v0, v1, 0, 1, 2, 3, 4, 5, 6, 7);
                oacc[b][m] = __builtin_amdgcn_mfma_f32_16x16x32_bf16(vf.v, pf.v, oacc[b][m], 0, 0, 0);
            }
        }
        __syncthreads();
    }
    // combine the two k-quarters (padded LDS: stride 68 floats)
    float* cb = (float*)lds;
    if (kq == 1) {
#pragma unroll
        for (int b = 0; b < 4; ++b)
#pragma unroll
            for (int m = 0; m < 4; ++m)
                *(f32x4*)&cb[(qsub * 64 + lane) * 68 + (b * 4 + m) * 4] = oacc[b][m];
    }
    __syncthreads();
    if (kq == 0) {
#pragma unroll
        for (int b = 0; b < 4; ++b)
#pragma unroll
            for (int m = 0; m < 4; ++m) {
                f32x4 v = oacc[b][m] + *(const f32x4*)&cb[(qsub * 64 + lane) * 68 + (b * 4 + m) * 4];
                u16x4 ov;
#pragma unroll
                for (int r = 0; r < 4; ++r) ov[r] = f2bf(v[r]);
                *(u16x4*)(o16 + (size_t)(b * 1024 + q0 + l15) * 1024 + ks * 512 + h * 64 + m * 16 + 4 * l4) = ov;
            }
    }
}

// ---------------- fused  ln_attn -> silu -> ln1  (one wave per row; bf16 in/out) ----------------
__global__ __launch_bounds__(64) void ln_fuse_k(const uint16_t* __restrict__ in,
    const float* __restrict__ g1, const float* __restrict__ b1,
    const float* __restrict__ g2, const float* __restrict__ b2,
    uint16_t* __restrict__ h16)
{
    const int row = blockIdx.x, lane = threadIdx.x;
    u16x8 iv = *(const u16x8*)(in + (size_t)row * 512 + lane * 8);
    float x[8];
#pragma unroll
    for (int i = 0; i < 8; ++i) x[i] = bf2f(iv[i]);
    float sum = 0.f, sq = 0.f;
#pragma unroll
    for (int i = 0; i < 8; ++i) { sum += x[i]; sq += x[i] * x[i]; }
    for (int m = 32; m; m >>= 1) { sum += __shfl_xor(sum, m); sq += __shfl_xor(sq, m); }
    float mu = sum * (1.f / 512.f);
    float rs = rsqrtf(sq * (1.f / 512.f) - mu * mu + 1e-5f);
    float y[8]; float s2 = 0.f, q2 = 0.f;
#pragma unroll
    for (int i = 0; i < 8; ++i) {
        int c = lane * 8 + i;
        float v = (x[i] - mu) * rs * g1[c] + b1[c];
        v = v * sigmoidf_(v);
        y[i] = v; s2 += v; q2 += v * v;
    }
    for (int m = 32; m; m >>= 1) { s2 += __shfl_xor(s2, m); q2 += __shfl_xor(q2, m); }
    float mu2 = s2 * (1.f / 512.f);
    float rs2 = rsqrtf(q2 * (1.f / 512.f) - mu2 * mu2 + 1e-5f);
    u16x8 ov;
#pragma unroll
    for (int i = 0; i < 8; ++i) {
        int c = lane * 8 + i;
        float v = (y[i] - mu2) * rs2 * g2[c] + b2[c];
        ov[i] = f2bf(v);
    }
    *(u16x8*)(h16 + (size_t)row * 512 + lane * 8) = ov;
}

// ---------------- x16 = ln2(f + h), bf16 in; LAST layer also computes regression head ----------------
template<int LAST>
__global__ __launch_bounds__(64) void ln_res_k(const uint16_t* __restrict__ f, const uint16_t* __restrict__ hres,
    const float* __restrict__ g, const float* __restrict__ bb, uint16_t* __restrict__ x16,
    const float* __restrict__ regW, const float* __restrict__ regb, float* __restrict__ out)
{
    const int row = blockIdx.x, lane = threadIdx.x;
    const size_t base = (size_t)row * 512 + lane * 8;
    u16x8 fv = *(const u16x8*)(f + base);
    u16x8 hv = *(const u16x8*)(hres + base);
    float x[8];
#pragma unroll
    for (int i = 0; i < 8; ++i) x[i] = bf2f(fv[i]) + bf2f(hv[i]);
    float sum = 0.f, sq = 0.f;
#pragma unroll
    for (int i = 0; i < 8; ++i) { sum += x[i]; sq += x[i] * x[i]; }
    for (int m = 32; m; m >>= 1) { sum += __shfl_xor(sum, m); sq += __shfl_xor(sq, m); }
    float mu = sum * (1.f / 512.f);
    float rs = rsqrtf(sq * (1.f / 512.f) - mu * mu + 1e-5f);
    float v[8];
#pragma unroll
    for (int i = 0; i < 8; ++i) {
        int c = lane * 8 + i;
        v[i] = (x[i] - mu) * rs * g[c] + bb[c];
    }
    if (!LAST) {
        u16x8 ov;
#pragma unroll
        for (int i = 0; i < 8; ++i) ov[i] = f2bf(v[i]);
        *(u16x8*)(x16 + base) = ov;
    } else {
        float acc[18];
#pragma unroll
        for (int j = 0; j < 18; ++j) acc[j] = 0.f;
#pragma unroll
        for (int i = 0; i < 8; ++i) {
            const float* wr = regW + (size_t)(lane * 8 + i) * 18;
#pragma unroll
            for (int j = 0; j < 18; ++j) acc[j] += v[i] * wr[j];
        }
#pragma unroll
        for (int j = 0; j < 18; ++j) {
            acc[j] += __shfl_xor(acc[j], 1);
            acc[j] += __shfl_xor(acc[j], 2);
            acc[j] += __shfl_xor(acc[j], 4);
            acc[j] += __shfl_xor(acc[j], 8);
            acc[j] += __shfl_xor(acc[j], 16);
            acc[j] += __shfl_xor(acc[j], 32);
        }
        if (lane == 0) {
#pragma unroll
            for (int j = 0; j < 18; ++j)
                out[(size_t)row * 18 + j] = acc[j] + regb[j];
        }
    }
}

// ---------------- launch ----------------
extern "C" void kernel_launch(void* const* d_in, const int* in_sizes, int n_in,
                              void* d_out, int out_size, void* d_ws, size_t ws_size,
                              hipStream_t stream)
{
    const float* features = (const float*)d_in[0];
    const float* target   = (const float*)d_in[1];
    const float* emb_W    = (const float*)d_in[4];
    const float* emb_b    = (const float*)d_in[5];
    const float* station  = (const float*)d_in[6];
    const float* Wq   = (const float*)d_in[7];
    const float* Wk   = (const float*)d_in[8];
    const float* Wv   = (const float*)d_in[9];
    const float* Wo   = (const float*)d_in[10];
    const float* attn_b = (const float*)d_in[11];
    const float* lng  = (const float*)d_in[12];
    const float* lnb  = (const float*)d_in[13];
    const float* W1   = (const float*)d_in[14];
    const float* b1   = (const float*)d_in[15];
    const float* W2   = (const float*)d_in[16];
    const float* b2   = (const float*)d_in[17];
    const float* ln1g = (const float*)d_in[18];
    const float* ln1b = (const float*)d_in[19];
    const float* ln2g = (const float*)d_in[20];
    const float* ln2b = (const float*)d_in[21];
    const float* regW = (const float*)d_in[22];
    const float* regb = (const float*)d_in[23];
    float* out = (float*)d_out;

    const size_t NEEDED = 73531392;
    if (ws_size < NEEDED) return;   // fail visibly (output stays poisoned) rather than corrupt

    char* ws = (char*)d_ws;
    uint16_t* wt   = (uint16_t*)(ws);             // 19,005,440 B bf16 weight arena
    uint16_t* x16  = (uint16_t*)(ws + 19005440);  // 4 MB
    uint16_t* qkv  = (uint16_t*)(ws + 23199744);  // 12 MB
    uint16_t* vt   = (uint16_t*)(ws + 35782656);  // 4 MB
    uint16_t* o16  = (uint16_t*)(ws + 39976960);  // 8 MB  [4096][1024] split-O
    uint16_t* t16  = (uint16_t*)(ws + 48365568);  // 4 MB  (bf16 o-proj / ffn2 output)
    uint16_t* h16  = (uint16_t*)(ws + 65142784);  // 4 MB  (post-ln1, residual + ffn1 input)
    uint16_t* f16  = (uint16_t*)(ws + 69337088);  // 4 MB
    uint16_t* fm16 = (uint16_t*)(ws + 56754176);  // 1 MB

    wconv_k<<<dim3(8, 8, 37), 256, 0, stream>>>(Wq, Wk, Wv, Wo, W1, W2, emb_W, wt);
    fmean_k<<<dim3(2048), 256, 0, stream>>>(features, fm16);
    // embedding GEMM with fused bias + station embedding (+NaN gating), writes x16 directly
    gemm64<1, 0, 1, 0, 1><<<dim3(8, 64), 256, 0, stream>>>(fm16, wt + 9437184u, emb_b, x16, 4096, 512, 128, target, station);

    for (int l = 0; l < 6; ++l) {
        // qkv projection; V third written transposed directly to vt (fused vtrans)
        gemm128<1><<<dim3(12, 32), 256, 0, stream>>>(x16, wt + (size_t)l * 786432u, qkv, 1536, 512, vt);
        attn_k<<<dim3(512), 256, 0, stream>>>(qkv, vt, o16);
        // o-proj (K=1024 split-O combine) -> bf16 t16
        gemm64<1, 0, 1, 1, 0><<<dim3(8, 64), 256, 0, stream>>>(o16, wt + 4718592u + (size_t)l * 262144u, attn_b + l * 512, t16, 4096, 512, 1024, nullptr, nullptr);
        ln_fuse_k<<<dim3(4096), 64, 0, stream>>>(t16, lng + l * 512, lnb + l * 512, ln1g + l * 512, ln1b + l * 512, h16);
        gemm64<1, 1, 1, 0, 0><<<dim3(8, 64), 256, 0, stream>>>(h16, wt + 6291456u + (size_t)l * 262144u, b1 + l * 512, f16, 4096, 512, 512, nullptr, nullptr);
        // ffn2 -> bf16 t16
        gemm64<1, 0, 1, 0, 0><<<dim3(8, 64), 256, 0, stream>>>(f16, wt + 7864320u + (size_t)l * 262144u, b2 + l * 512, t16, 4096, 512, 512, nullptr, nullptr);
        if (l < 5)
            ln_res_k<0><<<dim3(4096), 64, 0, stream>>>(t16, h16, ln2g + l * 512, ln2b + l * 512, x16, regW, regb, out);
        else
            ln_res_k<1><<<dim3(4096), 64, 0, stream>>>(t16, h16, ln2g + l * 512, ln2b + l * 512, x16, regW, regb, out);
    }
}